// Round 8
// baseline (196.068 us; speedup 1.0000x reference)
//
#include <hip/hip_runtime.h>

// proto-contrastive CE loss via bf16 MFMA, persistent waves + register prefetch.
// features [N=1e6, D=128] f32, labels [N] i32, prototypes [C=150, D=128] f32.
// out[0] = mean_n( logsumexp_c(f_hat·p_c/T) - f_hat·p_lbl/T )
//
// R8: R5's prefetch body WITHOUT a launch_bounds minimum. History:
//  - R4/R5/R6: any waves/EU cap made the allocator split VGPR/AGPR evenly
//    and spill the prefetch buffer (160 MB scratch writes, ~480 us).
//  - R7: stateless body, no spill, but all waves run in lockstep ->
//    convoy effect: wall = SUM of pipe demands (~1850 cy/tile) not max.
//  - Fix: keep register prefetch (breaks the convoy by hiding load latency
//    inside the compute body) and let the allocator run free (~165 regs,
//    ~12 waves/CU, zero spill).

#define NS 1000000
#define NC 150
#define NCP 160              // classes padded to 10 tiles of 16
#define FD 128
#define NTILE (NS / 16)      // 62500 16-sample tiles
#define NBLK 1024            // grid-stride persistent blocks
#define NWAVE (NBLK * 4)

static constexpr float INV_T  = 1.0f / 0.15f;
static constexpr float MB     = 1.0f / 0.15f;     // fixed LSE shift, |logit| <= 1/T
static constexpr float LOG2E  = 1.4426950408889634f;
static constexpr float B2     = -MB * LOG2E;      // exp(x-MB) = exp2(x*log2e + B2)

typedef __attribute__((ext_vector_type(8))) short short8;
typedef __attribute__((ext_vector_type(4))) float f32x4;

__device__ __forceinline__ short f2bf(float x) {
    unsigned u = __builtin_bit_cast(unsigned, x);
    unsigned r = (u + 0x7fffu + ((u >> 16) & 1u)) >> 16;   // RNE
    return (short)r;
}

// ---- prep: fp32 protos [150][128] -> bf16 padded [160][128] in ws ----
__global__ __launch_bounds__(256) void proto_prep(
    const float* __restrict__ protos, unsigned short* __restrict__ dst)
{
    const int tid = threadIdx.x;
#pragma unroll 4
    for (int i = 0; i < (NCP * FD) / 256; ++i) {
        int idx = i * 256 + tid;
        int row = idx >> 7;
        int col = idx & 127;
        float v = (row < NC) ? protos[row * FD + col] : 0.0f;
        dst[idx] = (unsigned short)f2bf(v);
    }
}

// ---- main: persistent, each wave grid-strides over 16-sample tiles ----
__global__ __launch_bounds__(256) void proto_ce_mfma(
    const float*          __restrict__ feats,
    const int*            __restrict__ labels,
    const unsigned short* __restrict__ protos_bf,  // [160][128] bf16 row-major
    double*               __restrict__ partials)
{
    __shared__ __align__(16) char lds[NCP * FD * 2];   // 40 KB, XOR-swizzled protos

    const int tid = threadIdx.x;

    // stage protos global->LDS, st-row swizzle: byte_in_row ^= (row&7)<<4
    {
        const uint4* src = (const uint4*)protos_bf;
#pragma unroll
        for (int i = 0; i < (NCP * FD * 2) / 16 / 256; ++i) {   // 10 iters
            int e8  = i * 256 + tid;
            int row = e8 >> 4;
            int binr = (e8 & 15) << 4;
            int dst = row * 256 + (binr ^ ((row & 7) << 4));
            *(uint4*)(lds + dst) = src[e8];
        }
    }
    __syncthreads();

    const int lane = tid & 63;
    const int wave = tid >> 6;
    const int col  = lane & 15;     // sample within tile / A-row within class tile
    const int grp  = lane >> 4;     // k-group
    const int gw   = blockIdx.x * 4 + wave;

    // swizzled LDS read address decomposition:
    // abyte(tt,kb) = (tt*16+col)*256 + ((kb*64+grp*16) ^ ((col&7)<<4))
    //             = a0 + (kb*64 ^ ahi) + tt*4096   (tt*4096 -> ds offset imm)
    const int sw  = (col & 7) << 4;
    const int a0  = col * 256 + ((grp * 16) ^ (sw & 0x30));
    const int ahi = sw & 0x40;

    const int lrel = -grp * 4;      // match when tt*16+r == lbl - grp*4
    const int vcnt = 6 - grp * 4;   // #valid r in class-tile 9 for this grp

    float4 buf[8];                  // one 16-sample tile slice: 8 x float4 per lane
    const long lane_off = (long)col * (FD / 4) + grp * 2;   // float4 units

    {   // prologue load, tile gw
        const float4* fp = (const float4*)(feats + (long)gw * (16 * FD)) + lane_off;
#pragma unroll
        for (int kb = 0; kb < 4; ++kb) {
            buf[kb * 2]     = fp[kb * 8];
            buf[kb * 2 + 1] = fp[kb * 8 + 1];
        }
    }

    float loss_acc = 0.0f;
    int t = gw;

    while (true) {
        // ---- per-sample L2 norm (fp32, raw floats; matches reference) ----
        float ssq = 0.0f;
#pragma unroll
        for (int i = 0; i < 8; ++i)
            ssq += buf[i].x * buf[i].x + buf[i].y * buf[i].y +
                   buf[i].z * buf[i].z + buf[i].w * buf[i].w;
        ssq += __shfl_xor(ssq, 16, 64);
        ssq += __shfl_xor(ssq, 32, 64);
        const float scl = rsqrtf(fmaxf(ssq, 1e-24f));

        const int lbl = labels[t * 16 + col];      // issued early, used in epilogue

        const int  tn   = t + NWAVE;
        const bool more = (tn < NTILE);
        const float4* fpn = (const float4*)(feats + (long)tn * (16 * FD)) + lane_off;

        f32x4 acc[10];
#pragma unroll
        for (int i = 0; i < 10; ++i) acc[i] = (f32x4){0.f, 0.f, 0.f, 0.f};

        // ---- per k-block: convert (frees 2 buf slots) -> prefetch into them
        //      -> 10x {ds_read + MFMA}. Only ONE short8 fragment live at a time.
#pragma unroll
        for (int kb = 0; kb < 4; ++kb) {
            float4 A = buf[kb * 2], Bv = buf[kb * 2 + 1];
            short8 bfr;
            bfr[0] = f2bf(A.x);  bfr[1] = f2bf(A.y);
            bfr[2] = f2bf(A.z);  bfr[3] = f2bf(A.w);
            bfr[4] = f2bf(Bv.x); bfr[5] = f2bf(Bv.y);
            bfr[6] = f2bf(Bv.z); bfr[7] = f2bf(Bv.w);

            if (more) {                          // prefetch next tile, same slots
                buf[kb * 2]     = fpn[kb * 8];
                buf[kb * 2 + 1] = fpn[kb * 8 + 1];
            }

            const char* ap = lds + (a0 + ((kb * 64) ^ ahi));
#pragma unroll
            for (int tt = 0; tt < 10; ++tt) {
                short8 af = *(const short8*)(ap + tt * 4096);
                acc[tt] = __builtin_amdgcn_mfma_f32_16x16x32_bf16(af, bfr, acc[tt], 0, 0, 0);
            }
        }

        // ---- epilogue: lane holds 40 raw logits (pre-scale) for sample `col` ----
        const float k2 = scl * (INV_T * LOG2E);
        const int   lm = lbl + lrel;            // match when tt*16+r == lm
        float s0 = 0.f, s1 = 0.f, s2 = 0.f, s3 = 0.f;
        float pick = 0.0f;
#pragma unroll
        for (int tt = 0; tt < 10; ++tt) {
#pragma unroll
            for (int r = 0; r < 4; ++r) {
                float a = acc[tt][r];
                float e = exp2f(fmaf(a, k2, B2));
                if (tt < 9) {
                    if      (r == 0) s0 += e;
                    else if (r == 1) s1 += e;
                    else if (r == 2) s2 += e;
                    else             s3 += e;
                } else {
                    s0 += (r < vcnt) ? e : 0.0f;   // mask padded classes 150..159
                }
                pick = (tt * 16 + r == lm) ? a : pick;
            }
        }
        float ssum = (s0 + s1) + (s2 + s3);
        ssum += __shfl_xor(ssum, 16, 64);
        ssum += __shfl_xor(ssum, 32, 64);
        pick += __shfl_xor(pick, 16, 64);
        pick += __shfl_xor(pick, 32, 64);

        loss_acc += __logf(ssum) + MB - pick * (scl * INV_T);

        if (!more) break;
        t = tn;
    }

    // sum the 16 samples (4 grp copies identical; reduce within 16-lane group)
    loss_acc += __shfl_xor(loss_acc, 1, 64);
    loss_acc += __shfl_xor(loss_acc, 2, 64);
    loss_acc += __shfl_xor(loss_acc, 4, 64);
    loss_acc += __shfl_xor(loss_acc, 8, 64);
    if (lane == 0)
        atomicAdd(&partials[gw & 255], (double)loss_acc);
}

__global__ __launch_bounds__(256) void proto_ce_final(
    const double* __restrict__ partials, float* __restrict__ out)
{
    const int tid = threadIdx.x;
    double v = partials[tid];
#pragma unroll
    for (int off = 32; off > 0; off >>= 1)
        v += __shfl_down(v, off, 64);
    __shared__ double w[4];
    if ((tid & 63) == 0) w[tid >> 6] = v;
    __syncthreads();
    if (tid == 0)
        out[0] = (float)((w[0] + w[1] + w[2] + w[3]) * (1.0 / (double)NS));
}

extern "C" void kernel_launch(void* const* d_in, const int* in_sizes, int n_in,
                              void* d_out, int out_size, void* d_ws, size_t ws_size,
                              hipStream_t stream)
{
    const float* feats  = (const float*)d_in[0];
    const int*   labels = (const int*)d_in[1];
    const float* protos = (const float*)d_in[2];

    unsigned short* protos_bf = (unsigned short*)d_ws;                 // 40960 B
    double* partials = (double*)((char*)d_ws + NCP * FD * 2);          // 2048 B

    (void)hipMemsetAsync(partials, 0, 256 * sizeof(double), stream);
    proto_prep<<<1, 256, 0, stream>>>(protos, protos_bf);
    proto_ce_mfma<<<NBLK, 256, 0, stream>>>(feats, labels, protos_bf, partials);
    proto_ce_final<<<1, 256, 0, stream>>>(partials, (float*)d_out);
}

// Round 9
// 167.928 us; speedup vs baseline: 1.1676x; 1.1676x over previous
//
#include <hip/hip_runtime.h>

// proto-contrastive CE loss via bf16 MFMA.
// R9: churny blocks (R2's winning structure) + fully-async staging.
//  - protos pre-swizzled in ws by prep -> linear global_load_lds DMA (40 KB)
//  - feature tile (64 samples x 512 B) DMA'd to LDS, swizzle applied on the
//    per-lane GLOBAL source address (linear LDS dest; m104/m173 pattern)
//  - waves carry no bulk load data in VGPRs: ds_read -> cvt -> MFMA -> epilogue
//  - 2 blocks/CU resident (72 KB LDS); block churn staggers stage/compute.

#define NS 1000000
#define NC 150
#define NCP 160
#define FD 128
#define NTILE (NS / 16)

static constexpr float INV_T = 1.0f / 0.15f;
static constexpr float MB    = 1.0f / 0.15f;
static constexpr float LOG2E = 1.4426950408889634f;
static constexpr float B2    = -MB * LOG2E;

typedef __attribute__((ext_vector_type(8))) short short8;
typedef __attribute__((ext_vector_type(4))) float f32x4;
typedef unsigned int u32;

#define GLOAD_LDS16(g, l) \
    __builtin_amdgcn_global_load_lds((const __attribute__((address_space(1))) u32*)(g), \
                                     (__attribute__((address_space(3))) u32*)(l), 16, 0, 0)

__device__ __forceinline__ unsigned f2bf_u(float x) {
    unsigned u = __builtin_bit_cast(unsigned, x);
    return (u + 0x7fffu + ((u >> 16) & 1u)) >> 16;   // RNE
}

// ---- prep: protos [150][128] f32 -> bf16, padded to 160 rows, PRE-SWIZZLED:
//      16B chunk cb of row r stored at chunk position cb ^ (r&7).
__global__ __launch_bounds__(256) void proto_prep(
    const float* __restrict__ protos, u32* __restrict__ dst)  // dst: 40960 B
{
    const int tid = threadIdx.x;
#pragma unroll
    for (int i = 0; i < 10; ++i) {            // 2560 chunks of 16 B
        int c  = i * 256 + tid;
        int r  = c >> 4;                      // row 0..159
        int cb = c & 15;                      // chunk in row (16 x 16B = 256 B)
        float f[8];
#pragma unroll
        for (int j = 0; j < 8; ++j)
            f[j] = (r < NC) ? protos[r * FD + cb * 8 + j] : 0.0f;
        u32 w[4];
#pragma unroll
        for (int j = 0; j < 4; ++j)
            w[j] = f2bf_u(f[2 * j]) | (f2bf_u(f[2 * j + 1]) << 16);
        u32* out = dst + (r * 64 + ((cb ^ (r & 7)) << 2));    // u32 units
        out[0] = w[0]; out[1] = w[1]; out[2] = w[2]; out[3] = w[3];
    }
}

// ---- main: block = 64 samples, 4 waves x 1 tile. Non-persistent (churn). ----
__global__ __launch_bounds__(256) void proto_ce_mfma(
    const float* __restrict__ feats,
    const int*   __restrict__ labels,
    const u32*   __restrict__ protos_sw,   // pre-swizzled bf16 [160][128]
    double*      __restrict__ partials)
{
    __shared__ __align__(16) char ldsA[NCP * FD * 2];   // 40960 B protos (swizzled)
    __shared__ __align__(16) char ldsF[64 * FD * 4];    // 32768 B features (swizzled)

    const int tid = threadIdx.x;

    // ---- async stage: all DMA issued back-to-back, one barrier ----
    {
        // protos: linear copy (already swizzled in ws)
        const char* ps = (const char*)protos_sw;
#pragma unroll
        for (int i = 0; i < 10; ++i) {
            int c = i * 256 + tid;                       // 16B chunk id
            GLOAD_LDS16(ps + c * 16, ldsA + c * 16);
        }
        // features: linear LDS dest, swizzled global src
        const char* fs = (const char*)(feats + (long)blockIdx.x * (64 * FD));
#pragma unroll
        for (int i = 0; i < 8; ++i) {
            int c = i * 256 + tid;                       // 2048 chunks
            int r = c >> 5;                              // sample row 0..63
            int x = c & 31;                              // chunk in 512B row
            GLOAD_LDS16(fs + r * 512 + ((x ^ (r & 7)) << 4), ldsF + c * 16);
        }
    }
    __syncthreads();   // compiler emits vmcnt(0) drain before barrier

    const int lane = tid & 63;
    const int wave = tid >> 6;
    const int col  = lane & 15;     // sample in tile / class-row in tile
    const int grp  = lane >> 4;     // k-group
    const int gw   = blockIdx.x * 4 + wave;

    // proto LDS read: chunk (kb*4+grp) of row (tt*16+col), stored ^ (row&7)
    const int sw  = (col & 7) << 4;
    const int a0  = col * 256 + ((grp * 16) ^ (sw & 0x30));
    const int ahi = sw & 0x40;

    // feature LDS read: row = wave*16+col; chunks (kb*8+grp*2 +{0,1}) ^ (col&7)
    const int frow = (wave * 16 + col) * 512;
    const int s3   = col & 7;
    const char* f0 = ldsF + frow + (((grp << 1) ^ s3) << 4);
    const char* f1 = ldsF + frow + ((((grp << 1) | 1) ^ s3) << 4);

    const int lrel = -grp * 4;
    const int vcnt = 6 - grp * 4;

    const int lbl = labels[gw * 16 + col];

    f32x4 acc[10];
#pragma unroll
    for (int i = 0; i < 10; ++i) acc[i] = (f32x4){0.f, 0.f, 0.f, 0.f};

    float ssq = 0.0f;
#pragma unroll
    for (int kb = 0; kb < 4; ++kb) {
        float4 A = *(const float4*)(f0 + kb * 128);
        float4 Bv = *(const float4*)(f1 + kb * 128);
        ssq += A.x * A.x + A.y * A.y + A.z * A.z + A.w * A.w;
        ssq += Bv.x * Bv.x + Bv.y * Bv.y + Bv.z * Bv.z + Bv.w * Bv.w;

        short8 bfr;
        bfr[0] = (short)f2bf_u(A.x);  bfr[1] = (short)f2bf_u(A.y);
        bfr[2] = (short)f2bf_u(A.z);  bfr[3] = (short)f2bf_u(A.w);
        bfr[4] = (short)f2bf_u(Bv.x); bfr[5] = (short)f2bf_u(Bv.y);
        bfr[6] = (short)f2bf_u(Bv.z); bfr[7] = (short)f2bf_u(Bv.w);

        const char* ap = ldsA + (a0 + ((kb * 64) ^ ahi));
#pragma unroll
        for (int tt = 0; tt < 10; ++tt) {
            short8 af = *(const short8*)(ap + tt * 4096);
            acc[tt] = __builtin_amdgcn_mfma_f32_16x16x32_bf16(af, bfr, acc[tt], 0, 0, 0);
        }
    }

    // norm across the 4 k-groups (scale applied post-MFMA)
    ssq += __shfl_xor(ssq, 16, 64);
    ssq += __shfl_xor(ssq, 32, 64);
    const float scl = rsqrtf(fmaxf(ssq, 1e-24f));

    // ---- epilogue: lane holds 40 raw logits for sample `col` ----
    const float k2 = scl * (INV_T * LOG2E);
    const int   lm = lbl + lrel;
    float s0 = 0.f, s1 = 0.f, s2 = 0.f, s3v = 0.f;
    float pick = 0.0f;
#pragma unroll
    for (int tt = 0; tt < 10; ++tt) {
#pragma unroll
        for (int r = 0; r < 4; ++r) {
            float a = acc[tt][r];
            float e = exp2f(fmaf(a, k2, B2));
            if (tt < 9) {
                if      (r == 0) s0 += e;
                else if (r == 1) s1 += e;
                else if (r == 2) s2 += e;
                else             s3v += e;
            } else {
                s0 += (r < vcnt) ? e : 0.0f;   // mask padded classes 150..159
            }
            pick = (tt * 16 + r == lm) ? a : pick;
        }
    }
    float ssum = (s0 + s1) + (s2 + s3v);
    ssum += __shfl_xor(ssum, 16, 64);
    ssum += __shfl_xor(ssum, 32, 64);
    pick += __shfl_xor(pick, 16, 64);
    pick += __shfl_xor(pick, 32, 64);

    float loss = __logf(ssum) + MB - pick * (scl * INV_T);

    // sum 16 samples (grp copies identical; reduce within 16-lane group)
    loss += __shfl_xor(loss, 1, 64);
    loss += __shfl_xor(loss, 2, 64);
    loss += __shfl_xor(loss, 4, 64);
    loss += __shfl_xor(loss, 8, 64);
    if (lane == 0)
        atomicAdd(&partials[gw & 255], (double)loss);
}

__global__ __launch_bounds__(256) void proto_ce_final(
    const double* __restrict__ partials, float* __restrict__ out)
{
    const int tid = threadIdx.x;
    double v = partials[tid];
#pragma unroll
    for (int off = 32; off > 0; off >>= 1)
        v += __shfl_down(v, off, 64);
    __shared__ double w[4];
    if ((tid & 63) == 0) w[tid >> 6] = v;
    __syncthreads();
    if (tid == 0)
        out[0] = (float)((w[0] + w[1] + w[2] + w[3]) * (1.0 / (double)NS));
}

extern "C" void kernel_launch(void* const* d_in, const int* in_sizes, int n_in,
                              void* d_out, int out_size, void* d_ws, size_t ws_size,
                              hipStream_t stream)
{
    const float* feats  = (const float*)d_in[0];
    const int*   labels = (const int*)d_in[1];
    const float* protos = (const float*)d_in[2];

    u32* protos_sw = (u32*)d_ws;                                  // 40960 B
    double* partials = (double*)((char*)d_ws + NCP * FD * 2);     // 2048 B

    (void)hipMemsetAsync(partials, 0, 256 * sizeof(double), stream);
    proto_prep<<<1, 256, 0, stream>>>(protos, protos_sw);
    proto_ce_mfma<<<NS / 64, 256, 0, stream>>>(feats, labels, protos_sw, partials);
    proto_ce_final<<<1, 256, 0, stream>>>(partials, (float*)d_out);
}